// Round 5
// baseline (431.880 us; speedup 1.0000x reference)
//
#include <hip/hip_runtime.h>
#include <stdint.h>

// Problem constants (ERA5 0.25deg -> CESM ~1deg)
#define N_A     1038240      // 721*1440 source cells (< 2^20, fits 20 bits)
#define NXSRC   1440
#define NYSRC   721
#define N_B     55296        // 192*288 destination cells
#define NNZ     221184       // 4 * N_B
#define M_LEAD  120          // 2 * 60 lead slices

#define K1      8            // fixed slots per dst row (Poisson(4): covers 99.2% of entries)
#define OVF_CAP 8192         // overflow list capacity (E[overflow] ~ 1825)
#define NXCD    8
#define BLK     256
#define BBLKS   (N_B / BLK)          // 216 b-blocks per plane
#define PLANES_XCD (M_LEAD / NXCD)   // 15 planes per XCD
#define WSCALE  4095.0f              // 12-bit weight quantization (err ~1.2e-4 << 0.22 thr)

#define CHUNKS   8                               // source chunks per plane
#define CHUNK_SZ ((N_A + CHUNKS - 1) / CHUNKS)   // 129,780 cells = 519 KB -> L2 window

// ws layout (bytes):
#define ENT8_OFF   0
#define CNT_OFF    1769472
#define OVFCNT_OFF 1990656
#define OVF_OFF    1990672
#define ZERO_BYTES 1990660   // ent8 + cnt + ovfcnt
#define WS_NEED    (OVF_OFF + OVF_CAP * 8)

// Build: packed = (a_flipped << 12) | w_q12 into ent8[r*8 + pos]; overflow -> list.
__global__ void build_kernel(const float* __restrict__ w,
                             const int* __restrict__ row,
                             const int* __restrict__ col,
                             int* __restrict__ cnt,
                             unsigned* __restrict__ ent8,
                             int* __restrict__ ovf_cnt,
                             uint2* __restrict__ ovf) {
    int i = blockIdx.x * blockDim.x + threadIdx.x;
    if (i >= NNZ) return;
    int r = row[i];
    int c = col[i];
    int lat = c / NXSRC;
    int lon = c - lat * NXSRC;
    unsigned a = (unsigned)((NYSRC - 1 - lat) * NXSRC + lon);  // latitude flip
    int wq = __float2int_rn(w[i] * WSCALE);
    wq = wq < 0 ? 0 : (wq > 4095 ? 4095 : wq);
    unsigned packed = (a << 12) | (unsigned)wq;
    int pos = atomicAdd(&cnt[r], 1);
    if (pos < K1) {
        ent8[r * K1 + pos] = packed;
    } else {
        int o = atomicAdd(ovf_cnt, 1);
        if (o < OVF_CAP) ovf[o] = make_uint2((unsigned)r, packed);
    }
}

// 1728 blocks (216 b-blocks x 8 XCDs), all co-resident. Entries loaded ONCE into
// regs. Per plane, walk 8 source-chunks in order; each thread touches only its
// entries inside the current 520 KB chunk -> bounded L2 reuse window, each x line
// fetched ~once per plane. waitcnt before each chunk's FMA phase-locks the walk.
__global__ __launch_bounds__(BLK) void gather_kernel(const float* __restrict__ x,
                                                     const uint4* __restrict__ ent4,
                                                     float* __restrict__ out) {
    unsigned l    = blockIdx.x;
    unsigned xcd  = l & (NXCD - 1);          // blockIdx % 8 -> XCD (dispatch heuristic)
    unsigned bblk = l >> 3;                  // 0..215
    unsigned b    = bblk * BLK + threadIdx.x;

    uint4 e0 = ent4[b * 2 + 0];
    uint4 e1 = ent4[b * 2 + 1];
    unsigned pk[K1] = {e0.x, e0.y, e0.z, e0.w, e1.x, e1.y, e1.z, e1.w};
    float    wf[K1];
    unsigned off[K1];
    unsigned ci[K1];
#pragma unroll
    for (int k = 0; k < K1; ++k) {
        wf[k]  = (float)(pk[k] & 0xFFFu) * (1.0f / WSCALE);
        off[k] = pk[k] >> 12;                 // packed==0 -> off 0, wf 0 (chunk 0, +0.0)
        ci[k]  = off[k] / CHUNK_SZ;           // const divide -> magic mul
    }

#pragma unroll 1
    for (int pix = 0; pix < PLANES_XCD; ++pix) {
        unsigned m = xcd * PLANES_XCD + pix;  // same (plane, chunk) order for whole XCD
        const float* __restrict__ xm = x + (size_t)m * N_A;
        float acc = 0.f;
#pragma unroll 1
        for (unsigned c = 0; c < CHUNKS; ++c) {
#pragma unroll
            for (int k = 0; k < K1; ++k) {
                if (ci[k] == c) acc += wf[k] * xm[off[k]];
            }
            __builtin_amdgcn_sched_barrier(0);  // no load hoisting across chunk phases
        }
        __builtin_nontemporal_store(acc, &out[(size_t)m * N_B + b]);
    }
}

// Overflow fixup: one thread per (overflow entry, m); ~219K atomics expected.
__global__ void fixup_kernel(const float* __restrict__ x,
                             const int* __restrict__ ovf_cnt,
                             const uint2* __restrict__ ovf,
                             float* __restrict__ out) {
    int t = blockIdx.x * blockDim.x + threadIdx.x;
    int e_idx = t / M_LEAD;
    int m = t - e_idx * M_LEAD;
    int n = *ovf_cnt;
    if (n > OVF_CAP) n = OVF_CAP;
    if (e_idx >= n) return;
    uint2 e = ovf[e_idx];
    float wv = (float)(e.y & 0xFFFu) * (1.0f / WSCALE);
    atomicAdd(&out[(size_t)m * N_B + e.x], wv * x[(size_t)m * N_A + (e.y >> 12)]);
}

// Fallback (tiny ws): zero output + atomic scatter-add.
__global__ void scatter_atomic_kernel(const float* __restrict__ x,
                                      const float* __restrict__ w,
                                      const int* __restrict__ row,
                                      const int* __restrict__ col,
                                      float* __restrict__ out) {
    int i = blockIdx.x * blockDim.x + threadIdx.x;
    if (i >= NNZ) return;
    int r = row[i];
    int c = col[i];
    int lat = c / NXSRC;
    int a   = (NYSRC - 1 - lat) * NXSRC + (c - lat * NXSRC);
    float wi = w[i];
    for (int m = 0; m < M_LEAD; ++m) {
        atomicAdd(&out[(size_t)m * N_B + r], wi * x[(size_t)m * N_A + a]);
    }
}

extern "C" void kernel_launch(void* const* d_in, const int* in_sizes, int n_in,
                              void* d_out, int out_size, void* d_ws, size_t ws_size,
                              hipStream_t stream) {
    const float* x   = (const float*)d_in[0];
    const float* w   = (const float*)d_in[1];
    const int*   row = (const int*)d_in[2];
    const int*   col = (const int*)d_in[3];
    float*       out = (float*)d_out;

    if (ws_size >= (size_t)WS_NEED) {
        unsigned* ent8    = (unsigned*)((char*)d_ws + ENT8_OFF);
        int*      cnt     = (int*)((char*)d_ws + CNT_OFF);
        int*      ovf_cnt = (int*)((char*)d_ws + OVFCNT_OFF);
        uint2*    ovf     = (uint2*)((char*)d_ws + OVF_OFF);

        hipMemsetAsync(d_ws, 0, ZERO_BYTES, stream);   // ent8 + cnt + ovf_cnt
        build_kernel<<<(NNZ + BLK - 1) / BLK, BLK, 0, stream>>>(
            w, row, col, cnt, ent8, ovf_cnt, ovf);

        gather_kernel<<<BBLKS * NXCD, BLK, 0, stream>>>(
            x, (const uint4*)ent8, out);

        fixup_kernel<<<(OVF_CAP * M_LEAD + BLK - 1) / BLK, BLK, 0, stream>>>(
            x, ovf_cnt, ovf, out);
    } else {
        hipMemsetAsync(out, 0, (size_t)M_LEAD * N_B * sizeof(float), stream);
        scatter_atomic_kernel<<<(NNZ + BLK - 1) / BLK, BLK, 0, stream>>>(
            x, w, row, col, out);
    }
}

// Round 6
// 336.278 us; speedup vs baseline: 1.2843x; 1.2843x over previous
//
#include <hip/hip_runtime.h>
#include <stdint.h>

// Problem constants (ERA5 0.25deg -> CESM ~1deg)
#define N_A     1038240      // 721*1440 source cells (< 2^20, fits 20 bits)
#define NXSRC   1440
#define NYSRC   721
#define N_B     55296        // 192*288 destination cells
#define NNZ     221184       // 4 * N_B
#define M_LEAD  120          // 2 * 60 lead slices

#define K1      8            // fixed slots per dst row (Poisson(4): covers 99.2% of entries)
#define OVF_CAP 8192         // overflow list capacity (E[overflow] ~ 1825)
#define NXCD    8
#define BLK     256
#define BBLKS   (N_B / BLK)          // 216 b-blocks per plane
#define PLANES_XCD (M_LEAD / NXCD)   // 15 planes per XCD
#define WSCALE  4095.0f              // 12-bit weight quantization (err ~1.2e-4 << 0.22 thr)

// ws layout (bytes):
//   xh     @ 0        : M_LEAD*N_A*2 = 249,177,600  (bf16 copy of x)
//   ent8   @ XH_B     : N_B*K1*4     =   1,769,472  (zero-padded packed entries)
//   cnt    @ +ent8    : N_B*4        =     221,184
//   ovfcnt @ +cnt     : 4 (+12 pad)
//   ovf    @ +16      : OVF_CAP*8    =      65,536
#define XH_B       249177600ULL
#define ENT8_OFF   (XH_B)
#define CNT_OFF    (XH_B + 1769472ULL)
#define OVFCNT_OFF (XH_B + 1990656ULL)
#define OVF_OFF    (XH_B + 1990672ULL)
#define ZERO_BYTES 1990660ULL        // ent8 + cnt + ovfcnt (memset from ENT8_OFF)
#define WS_NEED    (OVF_OFF + OVF_CAP * 8ULL)
#define WS_NEED_F32 2056208ULL       // mid-tier: ent8+cnt+ovfcnt+ovf without xh

// ---------------- build: packed = (a_flipped << 12) | w_q12 ----------------
__global__ void build_kernel(const float* __restrict__ w,
                             const int* __restrict__ row,
                             const int* __restrict__ col,
                             int* __restrict__ cnt,
                             unsigned* __restrict__ ent8,
                             int* __restrict__ ovf_cnt,
                             uint2* __restrict__ ovf) {
    int i = blockIdx.x * blockDim.x + threadIdx.x;
    if (i >= NNZ) return;
    int r = row[i];
    int c = col[i];
    int lat = c / NXSRC;
    int lon = c - lat * NXSRC;
    unsigned a = (unsigned)((NYSRC - 1 - lat) * NXSRC + lon);  // latitude flip
    int wq = __float2int_rn(w[i] * WSCALE);
    wq = wq < 0 ? 0 : (wq > 4095 ? 4095 : wq);
    unsigned packed = (a << 12) | (unsigned)wq;
    int pos = atomicAdd(&cnt[r], 1);
    if (pos < K1) {
        ent8[r * K1 + pos] = packed;
    } else {
        int o = atomicAdd(ovf_cnt, 1);
        if (o < OVF_CAP) ovf[o] = make_uint2((unsigned)r, packed);
    }
}

// ---------------- convert: x fp32 -> bf16 (RNE), pure streaming ----------------
__global__ __launch_bounds__(BLK) void convert_kernel(const float4* __restrict__ x4,
                                                      unsigned long long* __restrict__ xh8,
                                                      int n4) {
    int i = blockIdx.x * blockDim.x + threadIdx.x;
    int stride = gridDim.x * blockDim.x;
    for (; i < n4; i += stride) {
        float4 v = x4[i];
        unsigned u0 = __float_as_uint(v.x), u1 = __float_as_uint(v.y);
        unsigned u2 = __float_as_uint(v.z), u3 = __float_as_uint(v.w);
        // round-to-nearest-even bf16
        unsigned h0 = (u0 + 0x7FFFu + ((u0 >> 16) & 1u)) >> 16;
        unsigned h1 = (u1 + 0x7FFFu + ((u1 >> 16) & 1u)) >> 16;
        unsigned h2 = (u2 + 0x7FFFu + ((u2 >> 16) & 1u)) >> 16;
        unsigned h3 = (u3 + 0x7FFFu + ((u3 >> 16) & 1u)) >> 16;
        unsigned long long p = (unsigned long long)(h0 | (h1 << 16)) |
                               ((unsigned long long)(h2 | (h3 << 16)) << 32);
        __builtin_nontemporal_store(p, &xh8[i]);
    }
}

// ---------------- gather (bf16 plane, flat high-churn grid) ----------------
// 25920 blocks, thread per (m,b). XCD k owns planes [15k,15k+15) plane-major:
// working set per XCD = bf16 plane 2.07 MB + ent8 1.77 MB (shared by all its
// planes -> stays resident) = 3.84 MB < 4.19 MB L2.
__global__ __launch_bounds__(BLK) void gather_bf16_kernel(const unsigned short* __restrict__ xh,
                                                          const uint4* __restrict__ ent4,
                                                          float* __restrict__ out) {
    unsigned l    = blockIdx.x;
    unsigned xcd  = l & (NXCD - 1);          // blockIdx % 8 -> XCD (dispatch heuristic)
    unsigned slot = l >> 3;
    unsigned pix  = slot / BBLKS;            // plane within XCD (0..14)
    unsigned bblk = slot - pix * BBLKS;      // 0..215
    unsigned m    = xcd * PLANES_XCD + pix;
    unsigned b    = bblk * BLK + threadIdx.x;

    const unsigned short* __restrict__ xm = xh + (size_t)m * N_A;
    uint4 e0 = ent4[b * 2 + 0];
    uint4 e1 = ent4[b * 2 + 1];
    unsigned pk[K1] = {e0.x, e0.y, e0.z, e0.w, e1.x, e1.y, e1.z, e1.w};
    float acc = 0.f;
#pragma unroll
    for (int k = 0; k < K1; ++k) {
        float xv = __uint_as_float((unsigned)xm[pk[k] >> 12] << 16);  // bf16 -> f32
        acc += (float)(pk[k] & 0xFFFu) * xv;                          // packed==0 -> +0
    }
    __builtin_nontemporal_store(acc * (1.0f / WSCALE), &out[(size_t)m * N_B + b]);
}

// fp32 fallback gather (mid-tier ws) — round-3 verified path.
__global__ __launch_bounds__(BLK) void gather_f32_kernel(const float* __restrict__ x,
                                                         const uint4* __restrict__ ent4,
                                                         float* __restrict__ out) {
    unsigned l    = blockIdx.x;
    unsigned xcd  = l & (NXCD - 1);
    unsigned slot = l >> 3;
    unsigned pix  = slot / BBLKS;
    unsigned bblk = slot - pix * BBLKS;
    unsigned m    = xcd * PLANES_XCD + pix;
    unsigned b    = bblk * BLK + threadIdx.x;

    const float* __restrict__ xm = x + (size_t)m * N_A;
    uint4 e0 = ent4[b * 2 + 0];
    uint4 e1 = ent4[b * 2 + 1];
    unsigned pk[K1] = {e0.x, e0.y, e0.z, e0.w, e1.x, e1.y, e1.z, e1.w};
    float acc = 0.f;
#pragma unroll
    for (int k = 0; k < K1; ++k)
        acc += (float)(pk[k] & 0xFFFu) * xm[pk[k] >> 12];
    __builtin_nontemporal_store(acc * (1.0f / WSCALE), &out[(size_t)m * N_B + b]);
}

// Overflow fixup: one thread per (overflow entry, m); ~219K atomics expected.
__global__ void fixup_kernel(const float* __restrict__ x,
                             const int* __restrict__ ovf_cnt,
                             const uint2* __restrict__ ovf,
                             float* __restrict__ out) {
    int t = blockIdx.x * blockDim.x + threadIdx.x;
    int e_idx = t / M_LEAD;
    int m = t - e_idx * M_LEAD;
    int n = *ovf_cnt;
    if (n > OVF_CAP) n = OVF_CAP;
    if (e_idx >= n) return;
    uint2 e = ovf[e_idx];
    float wv = (float)(e.y & 0xFFFu) * (1.0f / WSCALE);
    atomicAdd(&out[(size_t)m * N_B + e.x], wv * x[(size_t)m * N_A + (e.y >> 12)]);
}

// Last-resort fallback (tiny ws): zero output + atomic scatter-add.
__global__ void scatter_atomic_kernel(const float* __restrict__ x,
                                      const float* __restrict__ w,
                                      const int* __restrict__ row,
                                      const int* __restrict__ col,
                                      float* __restrict__ out) {
    int i = blockIdx.x * blockDim.x + threadIdx.x;
    if (i >= NNZ) return;
    int r = row[i];
    int c = col[i];
    int lat = c / NXSRC;
    int a   = (NYSRC - 1 - lat) * NXSRC + (c - lat * NXSRC);
    float wi = w[i];
    for (int m = 0; m < M_LEAD; ++m) {
        atomicAdd(&out[(size_t)m * N_B + r], wi * x[(size_t)m * N_A + a]);
    }
}

extern "C" void kernel_launch(void* const* d_in, const int* in_sizes, int n_in,
                              void* d_out, int out_size, void* d_ws, size_t ws_size,
                              hipStream_t stream) {
    const float* x   = (const float*)d_in[0];
    const float* w   = (const float*)d_in[1];
    const int*   row = (const int*)d_in[2];
    const int*   col = (const int*)d_in[3];
    float*       out = (float*)d_out;

    if (ws_size >= WS_NEED) {
        unsigned short* xh      = (unsigned short*)d_ws;
        unsigned*       ent8    = (unsigned*)((char*)d_ws + ENT8_OFF);
        int*            cnt     = (int*)((char*)d_ws + CNT_OFF);
        int*            ovf_cnt = (int*)((char*)d_ws + OVFCNT_OFF);
        uint2*          ovf     = (uint2*)((char*)d_ws + OVF_OFF);

        hipMemsetAsync((char*)d_ws + ENT8_OFF, 0, ZERO_BYTES, stream);
        build_kernel<<<(NNZ + BLK - 1) / BLK, BLK, 0, stream>>>(
            w, row, col, cnt, ent8, ovf_cnt, ovf);

        const int n4 = (M_LEAD * N_A) / 4;   // 31,147,200 float4s
        convert_kernel<<<2048, BLK, 0, stream>>>(
            (const float4*)x, (unsigned long long*)xh, n4);

        gather_bf16_kernel<<<BBLKS * M_LEAD, BLK, 0, stream>>>(
            xh, (const uint4*)ent8, out);

        fixup_kernel<<<(OVF_CAP * M_LEAD + BLK - 1) / BLK, BLK, 0, stream>>>(
            x, ovf_cnt, ovf, out);
    } else if (ws_size >= WS_NEED_F32) {
        unsigned* ent8    = (unsigned*)((char*)d_ws + 0);
        int*      cnt     = (int*)((char*)d_ws + 1769472);
        int*      ovf_cnt = (int*)((char*)d_ws + 1990656);
        uint2*    ovf     = (uint2*)((char*)d_ws + 1990672);

        hipMemsetAsync(d_ws, 0, ZERO_BYTES, stream);
        build_kernel<<<(NNZ + BLK - 1) / BLK, BLK, 0, stream>>>(
            w, row, col, cnt, ent8, ovf_cnt, ovf);
        gather_f32_kernel<<<BBLKS * M_LEAD, BLK, 0, stream>>>(
            x, (const uint4*)ent8, out);
        fixup_kernel<<<(OVF_CAP * M_LEAD + BLK - 1) / BLK, BLK, 0, stream>>>(
            x, ovf_cnt, ovf, out);
    } else {
        hipMemsetAsync(out, 0, (size_t)M_LEAD * N_B * sizeof(float), stream);
        scatter_atomic_kernel<<<(NNZ + BLK - 1) / BLK, BLK, 0, stream>>>(
            x, w, row, col, out);
    }
}

// Round 7
// 291.119 us; speedup vs baseline: 1.4835x; 1.1551x over previous
//
#include <hip/hip_runtime.h>
#include <stdint.h>

// Problem constants (ERA5 0.25deg -> CESM ~1deg)
#define N_A     1038240      // 721*1440 source cells (< 2^20, fits 20 bits)
#define NXSRC   1440
#define NYSRC   721
#define N_B     55296        // 192*288 destination cells
#define NNZ     221184       // 4 * N_B
#define M_LEAD  120          // 2 * 60 lead slices

#define K1      8            // fixed slots per dst row (Poisson(4): covers 99.2% of entries)
#define OVF_CAP 8192         // overflow list capacity (E[overflow] ~ 1825)
#define NXCD    8
#define BLK     256
#define BBLKS   (N_B / BLK)          // 216 b-blocks per plane
#define PLANES_XCD (M_LEAD / NXCD)   // 15 planes per XCD
#define WSCALE  4095.0f              // 12-bit weight quantization (err ~1.2e-4 << 0.22 thr)
#define HALF    (N_A / 2)            // 519,120 : source split point

// ws layout (bytes):
//   ent8   @ 0         : N_B*K1*4 = 1,769,472   (zero-padded packed entries, per-b contiguous)
//   cnt    @ 1,769,472 : N_B*4    =   221,184
//   ovfcnt @ 1,990,656 : 4 (+12 pad)
//   ovf    @ 1,990,672 : OVF_CAP*8 =   65,536
#define ENT8_OFF   0
#define CNT_OFF    1769472
#define OVFCNT_OFF 1990656
#define OVF_OFF    1990672
#define ZERO_BYTES 1990660   // ent8 + cnt + ovfcnt
#define WS_NEED    (OVF_OFF + OVF_CAP * 8)

// Build: packed = (a_flipped << 12) | w_q12 into ent8[r*8 + pos]; overflow -> list.
__global__ void build_kernel(const float* __restrict__ w,
                             const int* __restrict__ row,
                             const int* __restrict__ col,
                             int* __restrict__ cnt,
                             unsigned* __restrict__ ent8,
                             int* __restrict__ ovf_cnt,
                             uint2* __restrict__ ovf) {
    int i = blockIdx.x * blockDim.x + threadIdx.x;
    if (i >= NNZ) return;
    int r = row[i];
    int c = col[i];
    int lat = c / NXSRC;
    int lon = c - lat * NXSRC;
    unsigned a = (unsigned)((NYSRC - 1 - lat) * NXSRC + lon);  // latitude flip
    int wq = __float2int_rn(w[i] * WSCALE);
    wq = wq < 0 ? 0 : (wq > 4095 ? 4095 : wq);
    unsigned packed = (a << 12) | (unsigned)wq;
    int pos = atomicAdd(&cnt[r], 1);
    if (pos < K1) {
        ent8[r * K1 + pos] = packed;
    } else {
        int o = atomicAdd(ovf_cnt, 1);
        if (o < OVF_CAP) ovf[o] = make_uint2((unsigned)r, packed);
    }
}

// Flat high-churn grid (25920 blocks), thread per (m,b); XCD k owns planes
// [15k,15k+15) plane-major. Called twice: phase 0 accumulates entries with
// off < HALF, phase 1 the rest (per-lane predicated -> no wrong-half traffic).
// Per-XCD L2 working set per phase = half-plane 2.08 MB + ent8 1.77 MB < 4.19 MB.
__global__ __launch_bounds__(BLK) void gather_phase_kernel(const float* __restrict__ x,
                                                           const uint4* __restrict__ ent4,
                                                           float* __restrict__ out,
                                                           int phase) {
    unsigned l    = blockIdx.x;
    unsigned xcd  = l & (NXCD - 1);          // blockIdx % 8 -> XCD (dispatch heuristic)
    unsigned slot = l >> 3;
    unsigned pix  = slot / BBLKS;            // plane within XCD (0..14)
    unsigned bblk = slot - pix * BBLKS;      // 0..215
    unsigned m    = xcd * PLANES_XCD + pix;
    unsigned b    = bblk * BLK + threadIdx.x;

    const float* __restrict__ xm = x + (size_t)m * N_A;
    uint4 e0 = ent4[b * 2 + 0];
    uint4 e1 = ent4[b * 2 + 1];
    unsigned pk[K1] = {e0.x, e0.y, e0.z, e0.w, e1.x, e1.y, e1.z, e1.w};
    float acc = 0.f;
#pragma unroll
    for (int k = 0; k < K1; ++k) {
        unsigned off = pk[k] >> 12;
        bool in = phase ? (off >= HALF) : (off < HALF);  // packed==0 -> phase0, +0.0
        if (in) acc += (float)(pk[k] & 0xFFFu) * xm[off];
    }
    size_t oi = (size_t)m * N_B + b;
    float res = acc * (1.0f / WSCALE);
    if (phase) res += out[oi];               // accumulate phase-0 partial
    __builtin_nontemporal_store(res, &out[oi]);
}

// Overflow fixup: one thread per (overflow entry, m); ~219K atomics expected.
__global__ void fixup_kernel(const float* __restrict__ x,
                             const int* __restrict__ ovf_cnt,
                             const uint2* __restrict__ ovf,
                             float* __restrict__ out) {
    int t = blockIdx.x * blockDim.x + threadIdx.x;
    int e_idx = t / M_LEAD;
    int m = t - e_idx * M_LEAD;
    int n = *ovf_cnt;
    if (n > OVF_CAP) n = OVF_CAP;
    if (e_idx >= n) return;
    uint2 e = ovf[e_idx];
    float wv = (float)(e.y & 0xFFFu) * (1.0f / WSCALE);
    atomicAdd(&out[(size_t)m * N_B + e.x], wv * x[(size_t)m * N_A + (e.y >> 12)]);
}

// Fallback (tiny ws): zero output + atomic scatter-add.
__global__ void scatter_atomic_kernel(const float* __restrict__ x,
                                      const float* __restrict__ w,
                                      const int* __restrict__ row,
                                      const int* __restrict__ col,
                                      float* __restrict__ out) {
    int i = blockIdx.x * blockDim.x + threadIdx.x;
    if (i >= NNZ) return;
    int r = row[i];
    int c = col[i];
    int lat = c / NXSRC;
    int a   = (NYSRC - 1 - lat) * NXSRC + (c - lat * NXSRC);
    float wi = w[i];
    for (int m = 0; m < M_LEAD; ++m) {
        atomicAdd(&out[(size_t)m * N_B + r], wi * x[(size_t)m * N_A + a]);
    }
}

extern "C" void kernel_launch(void* const* d_in, const int* in_sizes, int n_in,
                              void* d_out, int out_size, void* d_ws, size_t ws_size,
                              hipStream_t stream) {
    const float* x   = (const float*)d_in[0];
    const float* w   = (const float*)d_in[1];
    const int*   row = (const int*)d_in[2];
    const int*   col = (const int*)d_in[3];
    float*       out = (float*)d_out;

    if (ws_size >= (size_t)WS_NEED) {
        unsigned* ent8    = (unsigned*)((char*)d_ws + ENT8_OFF);
        int*      cnt     = (int*)((char*)d_ws + CNT_OFF);
        int*      ovf_cnt = (int*)((char*)d_ws + OVFCNT_OFF);
        uint2*    ovf     = (uint2*)((char*)d_ws + OVF_OFF);

        hipMemsetAsync(d_ws, 0, ZERO_BYTES, stream);   // ent8 + cnt + ovf_cnt
        build_kernel<<<(NNZ + BLK - 1) / BLK, BLK, 0, stream>>>(
            w, row, col, cnt, ent8, ovf_cnt, ovf);

        gather_phase_kernel<<<BBLKS * M_LEAD, BLK, 0, stream>>>(
            x, (const uint4*)ent8, out, 0);
        gather_phase_kernel<<<BBLKS * M_LEAD, BLK, 0, stream>>>(
            x, (const uint4*)ent8, out, 1);

        fixup_kernel<<<(OVF_CAP * M_LEAD + BLK - 1) / BLK, BLK, 0, stream>>>(
            x, ovf_cnt, ovf, out);
    } else {
        hipMemsetAsync(out, 0, (size_t)M_LEAD * N_B * sizeof(float), stream);
        scatter_atomic_kernel<<<(NNZ + BLK - 1) / BLK, BLK, 0, stream>>>(
            x, w, row, col, out);
    }
}